// Round 1
// baseline (351.439 us; speedup 1.0000x reference)
//
#include <hip/hip_runtime.h>

#define H 128
#define NPOS 1024
#define KNEG 10
#define NNEG (NPOS * KNEG)   // 10240
#define NTOT (NPOS + NNEG)   // 11264
#define NREL 1000
#define MAXL 256             // Poisson(11.26) max over 1000 rels << 256
#define QSPLIT 4
#define QROWS (H / QSPLIT)   // 32 rows of R per block

// 4 blocks (256 threads each) per RELATION; block (r,q) owns rows q*32..q*32+31
// of R (16 KiB staged in LDS -> ~7 blocks/CU resident vs 2 before). Each block
// computes the partial score sum_{i in quarter} h_i * (R_i . t) for its
// relation's triples and writes it to scores[q][n]; the loss kernel sums the
// 4 partials. HBM traffic is unchanged (quarters are disjoint), but the
// per-block serial chain {stage -> scan -> compute} is ~4x shorter and 3.5x
// more blocks are resident to hide latency.
__global__ __launch_bounds__(256) void rescal_rel_kernel(
    const float* __restrict__ ent,        // [ENT_TOTAL, H]
    const float* __restrict__ rel,        // [NREL, H*H]
    const int* __restrict__ pos_h, const int* __restrict__ pos_t,
    const int* __restrict__ pos_r,
    const int* __restrict__ neg_h, const int* __restrict__ neg_t,
    const int* __restrict__ neg_r,
    float* __restrict__ scores)           // [QSPLIT][NTOT] partials
{
    const int bid = blockIdx.x;
    const int r   = bid >> 2;             // relation
    const int q   = bid & 3;              // row-quarter
    const int tid = threadIdx.x;

    __shared__ float sR[QROWS * H];       // 16 KiB: rows q*32..q*32+31 of R
    __shared__ float sht[4][320];         // per-wave: h0[32] h1[32] t0[128] t1[128]
    __shared__ int   list[MAXL];
    __shared__ int   cnt;

    if (tid == 0) cnt = 0;
    __syncthreads();

    // ---- stage R quarter into LDS, coalesced float4 (4 per thread) ----
    {
        const float4* __restrict__ Rg =
            (const float4*)(rel + (size_t)r * (H * H) + (size_t)q * (QROWS * H));
        float4* __restrict__ Rs = (float4*)sR;
#pragma unroll
        for (int m4 = 0; m4 < 4; ++m4)
            Rs[m4 * 256 + tid] = Rg[m4 * 256 + tid];
    }

    // ---- vectorized scan of r-indices (int4), collect matching triples ----
    {
        const int4* __restrict__ pr4 = (const int4*)pos_r;
        const int4* __restrict__ nr4 = (const int4*)neg_r;
        for (int s = tid; s < NTOT / 4; s += 256) {
            int4 v; int base;
            if (s < NPOS / 4) { v = pr4[s];            base = s * 4; }
            else              { v = nr4[s - NPOS / 4]; base = NPOS + (s - NPOS / 4) * 4; }
            if (v.x == r) { int p = atomicAdd(&cnt, 1); if (p < MAXL) list[p] = base + 0; }
            if (v.y == r) { int p = atomicAdd(&cnt, 1); if (p < MAXL) list[p] = base + 1; }
            if (v.z == r) { int p = atomicAdd(&cnt, 1); if (p < MAXL) list[p] = base + 2; }
            if (v.w == r) { int p = atomicAdd(&cnt, 1); if (p < MAXL) list[p] = base + 3; }
        }
    }
    __syncthreads();

    const int m    = cnt < MAXL ? cnt : MAXL;
    const int wave = tid >> 6;
    const int lane = tid & 63;
    const int half = lane >> 5;           // 0: quarter-rows 0..15, 1: rows 16..31
    const int jcb  = lane & 31;           // float4 column block, j = 4*jcb

    float* __restrict__ hs0 = &sht[wave][0];    // h quarter, triple 0
    float* __restrict__ hs1 = &sht[wave][32];   // h quarter, triple 1
    float* __restrict__ ts0 = &sht[wave][64];   // t full, triple 0
    float* __restrict__ ts1 = &sht[wave][192];  // t full, triple 1

    float* __restrict__ sq = scores + (size_t)q * NTOT;

    auto fetch = [&](int i, float2& fh, float2& ft) {
        const int n  = list[i];
        const int hi = (n < NPOS) ? pos_h[n] : neg_h[n - NPOS];
        const int ti = (n < NPOS) ? pos_t[n] : neg_t[n - NPOS];
        // h: only this block's 32-row quarter (lanes 0-15 cover it; others dup)
        fh = ((const float2*)(ent + (size_t)hi * H + q * QROWS))[lane & 15];
        ft = ((const float2*)(ent + (size_t)ti * H))[lane];
    };

    int p = wave;                         // pair index; triples 2p, 2p+1
    float2 ph0, pt0, ph1, pt1;
    if (2 * p < m) {
        fetch(2 * p, ph0, pt0);
        fetch((2 * p + 1 < m) ? 2 * p + 1 : 2 * p, ph1, pt1);
    }

    while (2 * p < m) {
        const int  n0   = list[2 * p];
        const bool has1 = (2 * p + 1 < m);
        const int  n1   = has1 ? list[2 * p + 1] : n0;

        ((float2*)ts0)[lane] = pt0;
        ((float2*)ts1)[lane] = pt1;
        if (lane < 16) {
            ((float2*)hs0)[lane] = ph0;
            ((float2*)hs1)[lane] = ph1;
        }
        asm volatile("s_waitcnt lgkmcnt(0)" ::: "memory");

        // prefetch next pair's h/t (overlaps with compute)
        const int np = p + 4;
        if (2 * np < m) {
            fetch(2 * np, ph0, pt0);
            fetch((2 * np + 1 < m) ? 2 * np + 1 : 2 * np, ph1, pt1);
        }

        const float4  t04 = *(const float4*)&ts0[4 * jcb];
        const float4  t14 = *(const float4*)&ts1[4 * jcb];
        const float4* h0p = (const float4*)&hs0[half * 16];
        const float4* h1p = (const float4*)&hs1[half * 16];
        const float4* Rr4 = (const float4*)&sR[(size_t)(half * 16) * H];

        float acc0 = 0.f, acc1 = 0.f;
#pragma unroll
        for (int kk = 0; kk < 4; ++kk) {
            const float4 h04 = h0p[kk];
            const float4 h14 = h1p[kk];
#pragma unroll
            for (int d = 0; d < 4; ++d) {
                const float4 r4 = Rr4[(kk * 4 + d) * 32 + jcb];   // shared by both triples
                const float dot0 = r4.x * t04.x + r4.y * t04.y + r4.z * t04.z + r4.w * t04.w;
                const float dot1 = r4.x * t14.x + r4.y * t14.y + r4.z * t14.z + r4.w * t14.w;
                const float h0v = (d == 0) ? h04.x : (d == 1) ? h04.y : (d == 2) ? h04.z : h04.w;
                const float h1v = (d == 0) ? h14.x : (d == 1) ? h14.y : (d == 2) ? h14.z : h14.w;
                acc0 += h0v * dot0;
                acc1 += h1v * dot1;
            }
        }

#pragma unroll
        for (int mask = 32; mask > 0; mask >>= 1) {
            acc0 += __shfl_xor(acc0, mask, 64);
            acc1 += __shfl_xor(acc1, mask, 64);
        }
        if (lane == 0) {
            sq[n0] = acc0;
            if (has1) sq[n1] = acc1;
        }
        p = np;
    }
}

// Single block, 1024 threads: one thread per positive example.
// Sums the 4 row-quarter partials per triple.
__global__ __launch_bounds__(1024) void rescal_loss_kernel(
    const float* __restrict__ scores,     // [QSPLIT][NTOT]: pos then neg
    float* __restrict__ out)              // [1]
{
    const int b = threadIdx.x;

    float p = 0.0f;
#pragma unroll
    for (int qq = 0; qq < QSPLIT; ++qq) p += scores[(size_t)qq * NTOT + b];

    float ns = 0.0f;
#pragma unroll
    for (int k = 0; k < KNEG; ++k) {
        float s = 0.0f;
#pragma unroll
        for (int qq = 0; qq < QSPLIT; ++qq)
            s += scores[(size_t)qq * NTOT + NPOS + b * KNEG + k];
        ns += s;
    }
    ns *= (1.0f / KNEG);

    float l = fmaxf(ns - p + 1.0f, 0.0f);

#pragma unroll
    for (int off = 32; off > 0; off >>= 1)
        l += __shfl_down(l, off, 64);

    __shared__ float red[16];
    const int wave = b >> 6;
    if ((b & 63) == 0) red[wave] = l;
    __syncthreads();
    if (b == 0) {
        float s = 0.0f;
#pragma unroll
        for (int w = 0; w < 16; ++w) s += red[w];
        out[0] = s;
    }
}

extern "C" void kernel_launch(void* const* d_in, const int* in_sizes, int n_in,
                              void* d_out, int out_size, void* d_ws, size_t ws_size,
                              hipStream_t stream) {
    const float* ent   = (const float*)d_in[0];
    const float* rel   = (const float*)d_in[1];
    const int* pos_h   = (const int*)d_in[2];
    const int* pos_t   = (const int*)d_in[3];
    const int* pos_r   = (const int*)d_in[4];
    const int* neg_h   = (const int*)d_in[5];
    const int* neg_t   = (const int*)d_in[6];
    const int* neg_r   = (const int*)d_in[7];

    float* scores = (float*)d_ws;       // QSPLIT * NTOT floats = 176 KiB scratch
    float* out    = (float*)d_out;

    rescal_rel_kernel<<<NREL * QSPLIT, 256, 0, stream>>>(
        ent, rel, pos_h, pos_t, pos_r, neg_h, neg_t, neg_r, scores);
    rescal_loss_kernel<<<1, 1024, 0, stream>>>(scores, out);
}

// Round 2
// 345.590 us; speedup vs baseline: 1.0169x; 1.0169x over previous
//
#include <hip/hip_runtime.h>

#define H 128
#define NPOS 1024
#define KNEG 10
#define NNEG (NPOS * KNEG)   // 10240
#define NTOT (NPOS + NNEG)   // 11264
#define NREL 1000
#define MAXL 256             // Poisson(11.26) max over 1000 rels << 256
#define SCANU (NTOT / 4 / 256)  // 11 int4 scan loads per thread, exact

// One block (256 threads, 4 waves) per RELATION. R staged once in LDS (64 KiB).
// Each wave processes PAIRS of triples so every ds_read_b128 of R feeds two
// dot products (halves per-triple LDS traffic). Index-scan loads are issued
// BEFORE the staging loop so their L2 latency hides under the 64 KiB HBM
// staging stream.
__global__ __launch_bounds__(256) void rescal_rel_kernel(
    const float* __restrict__ ent,        // [ENT_TOTAL, H]
    const float* __restrict__ rel,        // [NREL, H*H]
    const int* __restrict__ pos_h, const int* __restrict__ pos_t,
    const int* __restrict__ pos_r,
    const int* __restrict__ neg_h, const int* __restrict__ neg_t,
    const int* __restrict__ neg_r,
    float* __restrict__ scores)           // [NTOT]
{
    const int r   = blockIdx.x;
    const int tid = threadIdx.x;

    __shared__ float sR[H * H];           // 64 KiB
    __shared__ float sht[4][4][H];        // per-wave {h0,t0,h1,t1} slots (8 KiB)
    __shared__ int   list[MAXL];
    __shared__ int   cnt;

    if (tid == 0) cnt = 0;
    __syncthreads();

    // ---- issue scan loads first (L2-hot after round 1; overlap with staging) ----
    int4 sv[SCANU];
    int  sbase[SCANU];
    {
        const int4* __restrict__ pr4 = (const int4*)pos_r;
        const int4* __restrict__ nr4 = (const int4*)neg_r;
#pragma unroll
        for (int u = 0; u < SCANU; ++u) {
            const int q = tid + u * 256;
            if (q < NPOS / 4) { sv[u] = pr4[q];            sbase[u] = q * 4; }
            else              { sv[u] = nr4[q - NPOS / 4]; sbase[u] = NPOS + (q - NPOS / 4) * 4; }
        }
    }

    // ---- stage R into LDS, coalesced float4 ----
    {
        const float4* __restrict__ Rg = (const float4*)(rel + (size_t)r * (H * H));
        float4* __restrict__ Rs = (float4*)sR;
#pragma unroll
        for (int m = 0; m < 16; ++m)
            Rs[m * 256 + tid] = Rg[m * 256 + tid];
    }

    // ---- compare phase: collect matching triples into list ----
    {
#pragma unroll
        for (int u = 0; u < SCANU; ++u) {
            const int4 v   = sv[u];
            const int base = sbase[u];
            if (v.x == r) { int p = atomicAdd(&cnt, 1); if (p < MAXL) list[p] = base + 0; }
            if (v.y == r) { int p = atomicAdd(&cnt, 1); if (p < MAXL) list[p] = base + 1; }
            if (v.z == r) { int p = atomicAdd(&cnt, 1); if (p < MAXL) list[p] = base + 2; }
            if (v.w == r) { int p = atomicAdd(&cnt, 1); if (p < MAXL) list[p] = base + 3; }
        }
    }
    __syncthreads();

    const int m    = cnt < MAXL ? cnt : MAXL;
    const int wave = tid >> 6;
    const int lane = tid & 63;
    const int half = lane >> 5;           // 0: rows 0..63, 1: rows 64..127
    const int jcb  = lane & 31;           // float4 column block, j = 4*jcb

    float* __restrict__ h0s = sht[wave][0];
    float* __restrict__ t0s = sht[wave][1];
    float* __restrict__ h1s = sht[wave][2];
    float* __restrict__ t1s = sht[wave][3];

    auto fetch = [&](int i, float2& fh, float2& ft) {
        const int n  = list[i];
        const int hi = (n < NPOS) ? pos_h[n] : neg_h[n - NPOS];
        const int ti = (n < NPOS) ? pos_t[n] : neg_t[n - NPOS];
        fh = ((const float2*)(ent + (size_t)hi * H))[lane];
        ft = ((const float2*)(ent + (size_t)ti * H))[lane];
    };

    int p = wave;                         // pair index; triples 2p, 2p+1
    float2 ph0, pt0, ph1, pt1;
    if (2 * p < m) {
        fetch(2 * p, ph0, pt0);
        fetch((2 * p + 1 < m) ? 2 * p + 1 : 2 * p, ph1, pt1);
    }

    while (2 * p < m) {
        const int  n0   = list[2 * p];
        const bool has1 = (2 * p + 1 < m);
        const int  n1   = has1 ? list[2 * p + 1] : n0;

        ((float2*)h0s)[lane] = ph0;
        ((float2*)t0s)[lane] = pt0;
        ((float2*)h1s)[lane] = ph1;
        ((float2*)t1s)[lane] = pt1;
        asm volatile("s_waitcnt lgkmcnt(0)" ::: "memory");

        // prefetch next pair's h/t (overlaps with compute)
        const int np = p + 4;
        if (2 * np < m) {
            fetch(2 * np, ph0, pt0);
            fetch((2 * np + 1 < m) ? 2 * np + 1 : 2 * np, ph1, pt1);
        }

        const float4  t04  = *(const float4*)&t0s[4 * jcb];
        const float4  t14  = *(const float4*)&t1s[4 * jcb];
        const float4* h04p = (const float4*)&h0s[half * 64];
        const float4* h14p = (const float4*)&h1s[half * 64];
        const float4* Rr4  = (const float4*)&sR[(size_t)half * 64 * H];

        float acc0 = 0.f, acc1 = 0.f;
#pragma unroll
        for (int kk = 0; kk < 16; ++kk) {
            const float4 h04 = h04p[kk];
            const float4 h14 = h14p[kk];
#pragma unroll
            for (int d = 0; d < 4; ++d) {
                const float4 r4 = Rr4[(kk * 4 + d) * 32 + jcb];   // shared by both triples
                const float dot0 = r4.x * t04.x + r4.y * t04.y + r4.z * t04.z + r4.w * t04.w;
                const float dot1 = r4.x * t14.x + r4.y * t14.y + r4.z * t14.z + r4.w * t14.w;
                const float h0v = (d == 0) ? h04.x : (d == 1) ? h04.y : (d == 2) ? h04.z : h04.w;
                const float h1v = (d == 0) ? h14.x : (d == 1) ? h14.y : (d == 2) ? h14.z : h14.w;
                acc0 += h0v * dot0;
                acc1 += h1v * dot1;
            }
        }

#pragma unroll
        for (int mask = 32; mask > 0; mask >>= 1) {
            acc0 += __shfl_xor(acc0, mask, 64);
            acc1 += __shfl_xor(acc1, mask, 64);
        }
        if (lane == 0) {
            scores[n0] = acc0;
            if (has1) scores[n1] = acc1;
        }
        p = np;
    }
}

// Single block, 1024 threads: one thread per positive example.
__global__ __launch_bounds__(1024) void rescal_loss_kernel(
    const float* __restrict__ scores,     // [NTOT]: pos then neg
    float* __restrict__ out)              // [1]
{
    const int b = threadIdx.x;
    const float p = scores[b];
    const float* __restrict__ neg = scores + NPOS + b * KNEG;
    float ns = 0.0f;
#pragma unroll
    for (int k = 0; k < KNEG; ++k) ns += neg[k];
    ns *= (1.0f / KNEG);

    float l = fmaxf(ns - p + 1.0f, 0.0f);

#pragma unroll
    for (int off = 32; off > 0; off >>= 1)
        l += __shfl_down(l, off, 64);

    __shared__ float red[16];
    const int wave = b >> 6;
    if ((b & 63) == 0) red[wave] = l;
    __syncthreads();
    if (b == 0) {
        float s = 0.0f;
#pragma unroll
        for (int w = 0; w < 16; ++w) s += red[w];
        out[0] = s;
    }
}

extern "C" void kernel_launch(void* const* d_in, const int* in_sizes, int n_in,
                              void* d_out, int out_size, void* d_ws, size_t ws_size,
                              hipStream_t stream) {
    const float* ent   = (const float*)d_in[0];
    const float* rel   = (const float*)d_in[1];
    const int* pos_h   = (const int*)d_in[2];
    const int* pos_t   = (const int*)d_in[3];
    const int* pos_r   = (const int*)d_in[4];
    const int* neg_h   = (const int*)d_in[5];
    const int* neg_t   = (const int*)d_in[6];
    const int* neg_r   = (const int*)d_in[7];

    float* scores = (float*)d_ws;       // NTOT floats = 45 KiB scratch
    float* out    = (float*)d_out;

    rescal_rel_kernel<<<NREL, 256, 0, stream>>>(
        ent, rel, pos_h, pos_t, pos_r, neg_h, neg_t, neg_r, scores);
    rescal_loss_kernel<<<1, 1024, 0, stream>>>(scores, out);
}